// Round 1
// baseline (723.563 us; speedup 1.0000x reference)
//
#include <hip/hip_runtime.h>

#define TT 512
#define BB 4096

__device__ __forceinline__ float fast_rcp(float x) { return __builtin_amdgcn_rcpf(x); }

__device__ __forceinline__ float sigmoid_f(float x) {
    float e = __expf(-x);
    return fast_rcp(1.0f + e);
}

__device__ __forceinline__ float tanh_f(float x) {
    // tanh(x) = 2/(1+exp(-2x)) - 1 ; stable for large |x|
    float e = __expf(-2.0f * x);
    return fmaf(2.0f, fast_rcp(1.0f + e), -1.0f);
}

// 32 lanes per batch element: lane = (o in 0..15 [output unit], half in 0..1 [K-split]).
// Block = 256 threads = 8 batch elements. Grid = 4096/8 = 512 blocks.
__global__ __launch_bounds__(256, 2)
void gru_fused_kernel(const float* __restrict__ x, const float* __restrict__ h0,
                      const float* __restrict__ W_emb, const float* __restrict__ b_emb,
                      const float* __restrict__ W_out, const float* __restrict__ b_out,
                      const float* __restrict__ Wih0, const float* __restrict__ Whh0,
                      const float* __restrict__ bih0, const float* __restrict__ bhh0,
                      const float* __restrict__ Wih1, const float* __restrict__ Whh1,
                      const float* __restrict__ bih1, const float* __restrict__ bhh1,
                      const float* __restrict__ Wih2, const float* __restrict__ Whh2,
                      const float* __restrict__ bih2, const float* __restrict__ bhh2,
                      float* __restrict__ out)
{
    const int tid  = threadIdx.x;
    const int grp  = tid >> 5;        // 0..7  batch element within block
    const int l32  = tid & 31;        // lane within group
    const int o    = l32 & 15;        // output unit
    const int half = l32 >> 4;        // K-half
    const int j0   = half * 8;        // K-offset
    const int b    = blockIdx.x * 8 + grp;

    __shared__ float hbuf[8][3][32];  // per-group per-layer h broadcast (slots 16..31 are write-dump)
    __shared__ float ebuf[8][32];     // embedding broadcast

    const float* WihA[3] = {Wih0, Wih1, Wih2};
    const float* WhhA[3] = {Whh0, Whh1, Whh2};
    const float* bihA[3] = {bih0, bih1, bih2};
    const float* bhhA[3] = {bhh0, bhh1, bhh2};

    // Register-cached weights: wih[L][gate][jj] = W_ih_L[gate*16+o][j0+jj]
    float wih[3][3][8], whh[3][3][8];
    float bias_r[3], bias_z[3], bias_xn[3], bias_hn[3];
#pragma unroll
    for (int L = 0; L < 3; ++L) {
#pragma unroll
        for (int g = 0; g < 3; ++g) {
            const float4 a0 = *(const float4*)(WihA[L] + (g * 16 + o) * 16 + j0);
            const float4 a1 = *(const float4*)(WihA[L] + (g * 16 + o) * 16 + j0 + 4);
            wih[L][g][0] = a0.x; wih[L][g][1] = a0.y; wih[L][g][2] = a0.z; wih[L][g][3] = a0.w;
            wih[L][g][4] = a1.x; wih[L][g][5] = a1.y; wih[L][g][6] = a1.z; wih[L][g][7] = a1.w;
            const float4 c0 = *(const float4*)(WhhA[L] + (g * 16 + o) * 16 + j0);
            const float4 c1 = *(const float4*)(WhhA[L] + (g * 16 + o) * 16 + j0 + 4);
            whh[L][g][0] = c0.x; whh[L][g][1] = c0.y; whh[L][g][2] = c0.z; whh[L][g][3] = c0.w;
            whh[L][g][4] = c1.x; whh[L][g][5] = c1.y; whh[L][g][6] = c1.z; whh[L][g][7] = c1.w;
        }
        bias_r[L]  = bihA[L][o]      + bhhA[L][o];
        bias_z[L]  = bihA[L][16 + o] + bhhA[L][16 + o];
        bias_xn[L] = bihA[L][32 + o];
        bias_hn[L] = bhhA[L][32 + o];
    }

    const float2 we = *(const float2*)(W_emb + o * 2);
    const float  be = b_emb[o];
    const float  wo0 = W_out[o], wo1 = W_out[16 + o];
    const float  bo0 = b_out[0], bo1 = b_out[1];

    float hreg[3];
#pragma unroll
    for (int L = 0; L < 3; ++L) hreg[L] = h0[(L * BB + b) * 16 + o];
#pragma unroll
    for (int L = 0; L < 3; ++L) hbuf[grp][L][half * 16 + o] = hreg[L];
    asm volatile("s_waitcnt lgkmcnt(0)" ::: "memory");

    const float* xb   = x + (size_t)b * (TT * 2);
    float*       outb = out + (size_t)b * (TT * 2);
    float2 xc = *(const float2*)(xb);

    for (int t = 0; t < TT; ++t) {
        float2 xnext = make_float2(0.f, 0.f);
        if (t + 1 < TT) xnext = *(const float2*)(xb + (t + 1) * 2);

        // Embedding: e[o] = relu(b_emb[o] + W_emb[o]·x_t)
        float e = fmaf(we.y, xc.y, fmaf(we.x, xc.x, be));
        e = fmaxf(e, 0.0f);
        ebuf[grp][half * 16 + o] = e;
        asm volatile("s_waitcnt lgkmcnt(0)" ::: "memory");

#pragma unroll
        for (int L = 0; L < 3; ++L) {
            const float4 i0 = (L == 0) ? *(const float4*)(&ebuf[grp][j0])
                                       : *(const float4*)(&hbuf[grp][L - 1][j0]);
            const float4 i1 = (L == 0) ? *(const float4*)(&ebuf[grp][j0 + 4])
                                       : *(const float4*)(&hbuf[grp][L - 1][j0 + 4]);
            const float4 h0v = *(const float4*)(&hbuf[grp][L][j0]);
            const float4 h1v = *(const float4*)(&hbuf[grp][L][j0 + 4]);
            float in8[8] = {i0.x, i0.y, i0.z, i0.w, i1.x, i1.y, i1.z, i1.w};
            float hh8[8] = {h0v.x, h0v.y, h0v.z, h0v.w, h1v.x, h1v.y, h1v.z, h1v.w};

            float xr = 0.f, xz = 0.f, xn = 0.f, hr = 0.f, hz = 0.f, hn = 0.f;
#pragma unroll
            for (int j = 0; j < 8; ++j) {
                xr = fmaf(wih[L][0][j], in8[j], xr);
                xz = fmaf(wih[L][1][j], in8[j], xz);
                xn = fmaf(wih[L][2][j], in8[j], xn);
                hr = fmaf(whh[L][0][j], hh8[j], hr);
                hz = fmaf(whh[L][1][j], hh8[j], hz);
                hn = fmaf(whh[L][2][j], hh8[j], hn);
            }
            xr += __shfl_xor(xr, 16);
            xz += __shfl_xor(xz, 16);
            xn += __shfl_xor(xn, 16);
            hr += __shfl_xor(hr, 16);
            hz += __shfl_xor(hz, 16);
            hn += __shfl_xor(hn, 16);

            const float r = sigmoid_f(xr + hr + bias_r[L]);
            const float z = sigmoid_f(xz + hz + bias_z[L]);
            const float n = tanh_f(fmaf(r, hn + bias_hn[L], xn + bias_xn[L]));
            const float hold = hreg[L];
            const float hnew = fmaf(z, hold - n, n);  // (1-z)*n + z*h
            hreg[L] = hnew;
            hbuf[grp][L][half * 16 + o] = hnew;
            asm volatile("s_waitcnt lgkmcnt(0)" ::: "memory");
        }

        float p0 = wo0 * hreg[2];
        float p1 = wo1 * hreg[2];
#pragma unroll
        for (int m = 1; m <= 8; m <<= 1) {
            p0 += __shfl_xor(p0, m);
            p1 += __shfl_xor(p1, m);
        }
        if (l32 == 0) {
            *(float2*)(outb + t * 2) = make_float2(p0 + bo0, p1 + bo1);
        }
        xc = xnext;
    }

    if (half == 0) {
#pragma unroll
        for (int L = 0; L < 3; ++L)
            out[(size_t)BB * TT * 2 + (L * BB + b) * 16 + o] = hreg[L];
    }
}

extern "C" void kernel_launch(void* const* d_in, const int* in_sizes, int n_in,
                              void* d_out, int out_size, void* d_ws, size_t ws_size,
                              hipStream_t stream) {
    const float* x     = (const float*)d_in[0];
    const float* h0    = (const float*)d_in[1];
    const float* W_emb = (const float*)d_in[2];
    const float* b_emb = (const float*)d_in[3];
    const float* W_out = (const float*)d_in[4];
    const float* b_out = (const float*)d_in[5];
    const float* Wih0  = (const float*)d_in[6];
    const float* Whh0  = (const float*)d_in[7];
    const float* bih0  = (const float*)d_in[8];
    const float* bhh0  = (const float*)d_in[9];
    const float* Wih1  = (const float*)d_in[10];
    const float* Whh1  = (const float*)d_in[11];
    const float* bih1  = (const float*)d_in[12];
    const float* bhh1  = (const float*)d_in[13];
    const float* Wih2  = (const float*)d_in[14];
    const float* Whh2  = (const float*)d_in[15];
    const float* bih2  = (const float*)d_in[16];
    const float* bhh2  = (const float*)d_in[17];
    float* out = (float*)d_out;

    gru_fused_kernel<<<dim3(BB / 8), dim3(256), 0, stream>>>(
        x, h0, W_emb, b_emb, W_out, b_out,
        Wih0, Whh0, bih0, bhh0,
        Wih1, Whh1, bih1, bhh1,
        Wih2, Whh2, bih2, bhh2,
        out);
}